// Round 1
// baseline (358.144 us; speedup 1.0000x reference)
//
#include <hip/hip_runtime.h>
#include <hip/hip_bf16.h>
#include <stdint.h>

typedef __attribute__((ext_vector_type(4))) float f32x4;
typedef __attribute__((ext_vector_type(8))) __bf16 bf16x8;
typedef unsigned short u16;
typedef unsigned long long u64;

__device__ __forceinline__ u16 f2bf(float f){
  unsigned u = __float_as_uint(f);
  u += 0x7fffu + ((u >> 16) & 1u);
  return (u16)(u >> 16);
}

__device__ __forceinline__ void gload16(const u16* g, u16* l){
  __builtin_amdgcn_global_load_lds(
      (__attribute__((address_space(1))) void*)g,
      (__attribute__((address_space(3))) void*)l, 16, 0, 0);
}

// ---- fp32 row matrix -> bf16 copy + numpy-pairwise row sum-of-squares ----
// numpy pairwise_sum(n=2048): 16 leaves of 128 (8-accumulator unrolled loop,
// ((r0+r1)+(r2+r3))+((r4+r5)+(r6+r7))), balanced binary combine tree.
__global__ __launch_bounds__(64)
void cvt_rows(const float* __restrict__ src, u16* __restrict__ dst,
              float* __restrict__ sq)
{
#pragma clang fp contract(off)
  const int row = blockIdx.x;
  const int l = threadIdx.x;
  const float* r = src + (size_t)row * 2048;
  const f32x4* r4 = (const f32x4*)r;
  ushort4* d4 = (ushort4*)(dst + (size_t)row * 2048);
#pragma unroll
  for (int i = 0; i < 8; i++){
    f32x4 v = r4[l + 64*i];
    ushort4 o;
    o.x = f2bf(v.x); o.y = f2bf(v.y); o.z = f2bf(v.z); o.w = f2bf(v.w);
    d4[l + 64*i] = o;
  }
  float leaf = 0.f;
  if (l < 16){
    const float* p = r + l*128;
    float rr[8];
#pragma unroll
    for (int j = 0; j < 8; j++){ float v = p[j]; rr[j] = v*v; }
    for (int i = 8; i < 128; i += 8){
#pragma unroll
      for (int j = 0; j < 8; j++){ float v = p[i+j]; float vv = v*v; rr[j] = rr[j] + vv; }
    }
    leaf = ((rr[0]+rr[1])+(rr[2]+rr[3]))+((rr[4]+rr[5])+(rr[6]+rr[7]));
  }
#pragma unroll
  for (int s = 1; s < 16; s <<= 1){
    float o = __shfl_down(leaf, s);
    if ((l & (2*s - 1)) == 0) leaf = leaf + o;
  }
  if (l == 0) sq[row] = leaf;
}

// ---- generic fp32 -> bf16 elementwise ----
__global__ __launch_bounds__(256)
void cvt_mat(const float* __restrict__ src, u16* __restrict__ dst, int n4)
{
  const f32x4* s4 = (const f32x4*)src;
  ushort4* d4 = (ushort4*)dst;
  for (int i = blockIdx.x*256 + threadIdx.x; i < n4; i += gridDim.x*256){
    f32x4 v = s4[i];
    ushort4 o;
    o.x = f2bf(v.x); o.y = f2bf(v.y); o.z = f2bf(v.z); o.w = f2bf(v.w);
    d4[i] = o;
  }
}

// ---- bf16 GEMM C = A[M,K] * B[N,K]^T, m97-style 128x128 tile, BK=32 ----
// EPI 0: store fp32 C (ldc=N).  EPI 1: relu(C+bias) -> bf16 (ldc=N).
// EPI 2: C+bias -> fp32, packed ldc=ncols, store guard col<ncols.
template<int EPI>
__global__ __launch_bounds__(256)
void gemm_bt(const u16* __restrict__ A, const u16* __restrict__ Bm,
             float* __restrict__ Cf, u16* __restrict__ Cb,
             const float* __restrict__ bias,
             int M, int N, int K, int ncols)
{
  __shared__ u16 As[128*32];
  __shared__ u16 Bs[128*32];
  const int t = threadIdx.x;
  const int bm = blockIdx.x, bn = blockIdx.y;
  const int brow = bm*128, bcol = bn*128;
  const int l = t & 63, w = t >> 6;
  const int wr = (w >> 1)*64, wc = (w & 1)*64;
  const int fr = l & 15, fk = (l >> 4)*8;
  f32x4 acc[4][4] = {};

  const int srow = t >> 2;
  const int skoff = (t & 3)*8;
  const u16* Ag = A + (size_t)(brow + srow)*K + skoff;
  const u16* Bg = Bm + (size_t)(bcol + srow)*K + skoff;
  u16* lA = As + t*8;
  u16* lB = Bs + t*8;

  for (int k0 = 0; k0 < K; k0 += 32){
    gload16(Ag + k0, lA);
    gload16(Ag + (size_t)64*K + k0, lA + 2048);
    gload16(Bg + k0, lB);
    gload16(Bg + (size_t)64*K + k0, lB + 2048);
    __syncthreads();
    bf16x8 av[4], bv[4];
#pragma unroll
    for (int m = 0; m < 4; m++)
      av[m] = *(const bf16x8*)(As + (wr + m*16 + fr)*32 + fk);
#pragma unroll
    for (int n = 0; n < 4; n++)
      bv[n] = *(const bf16x8*)(Bs + (wc + n*16 + fr)*32 + fk);
#pragma unroll
    for (int m = 0; m < 4; m++)
#pragma unroll
      for (int n = 0; n < 4; n++)
        acc[m][n] = __builtin_amdgcn_mfma_f32_16x16x32_bf16(av[m], bv[n], acc[m][n], 0, 0, 0);
    __syncthreads();
  }

#pragma unroll
  for (int n = 0; n < 4; n++){
    const int gcol = bcol + wc + n*16 + fr;
    float bvv = 0.f;
    if (EPI == 1) bvv = bias[gcol];
    if (EPI == 2 && gcol < ncols) bvv = bias[gcol];
#pragma unroll
    for (int m = 0; m < 4; m++){
      const int grow = brow + wr + m*16 + (l >> 4)*4;
#pragma unroll
      for (int r = 0; r < 4; r++){
        float v = acc[m][n][r];
        if (EPI == 0){
          Cf[(size_t)(grow + r)*N + gcol] = v;
        } else if (EPI == 1){
          v = fmaxf(v + bvv, 0.f);
          Cb[(size_t)(grow + r)*N + gcol] = f2bf(v);
        } else {
          if (gcol < ncols) Cf[(size_t)(grow + r)*ncols + gcol] = v + bvv;
        }
      }
    }
  }
}

// ---- per-row: distances, argmin (exact fp64-refined candidates), softmax ----
__global__ __launch_bounds__(256)
void row_softmax(const float* __restrict__ S, const float* __restrict__ x2,
                 const float* __restrict__ w2sq,
                 const float* __restrict__ x, const float* __restrict__ W,
                 u16* __restrict__ soft, float* __restrict__ winners)
{
  const int b = blockIdx.x, t = threadIdx.x;
  const float x2b = x2[b];
  const f32x4* S4 = (const f32x4*)(S + (size_t)b*4096);
  const f32x4* W24 = (const f32x4*)w2sq;
  float dv[16];
  float bd = 3.0e38f; int bc = 0;
#pragma unroll
  for (int i = 0; i < 4; i++){
    f32x4 s = S4[t + 256*i];
    f32x4 wv = W24[t + 256*i];
#pragma unroll
    for (int j = 0; j < 4; j++){
      float u = x2b + wv[j];
      float d2 = u - 2.0f*s[j];
      float d = __fsqrt_rn(fmaxf(d2, 1e-12f));
      dv[i*4 + j] = d;
      if (d < bd){ bd = d; bc = (t + 256*i)*4 + j; }
    }
  }
  u64 key = ((u64)__float_as_uint(bd) << 32) | (unsigned)bc;
#pragma unroll
  for (int s = 1; s < 64; s <<= 1){
    u64 o = __shfl_xor(key, s);
    if (o < key) key = o;
  }
  __shared__ u64 wk[4];
  __shared__ double csum[4];
  __shared__ float fred[4];
  __shared__ int ccnt;
  __shared__ int cand[32];
  if ((t & 63) == 0) wk[t >> 6] = key;
  if (t == 0) ccnt = 0;
  __syncthreads();
  u64 k0 = wk[0];
  if (wk[1] < k0) k0 = wk[1];
  if (wk[2] < k0) k0 = wk[2];
  if (wk[3] < k0) k0 = wk[3];
  const float dmin = __uint_as_float((unsigned)(k0 >> 32));

  const float thr = dmin + 0.01f;   // >100 sigma of bf16-GEMM noise on d
#pragma unroll
  for (int i = 0; i < 4; i++)
#pragma unroll
    for (int j = 0; j < 4; j++)
      if (dv[i*4 + j] <= thr){
        int p = atomicAdd(&ccnt, 1);
        if (p < 32) cand[p] = (t + 256*i)*4 + j;
      }
  __syncthreads();
  const int nc = min(ccnt, 32);

  float bestd = 3.0e38f; int besti = 0x7fffffff;
  const f32x4* xp = (const f32x4*)(x + (size_t)b*2048) + t*2;
  f32x4 xv0 = xp[0], xv1 = xp[1];
  for (int c = 0; c < nc; c++){
    const int h = cand[c];
    const f32x4* wp = (const f32x4*)(W + (size_t)h*2048) + t*2;
    f32x4 wv0 = wp[0], wv1 = wp[1];
    double a = 0.0;
#pragma unroll
    for (int j = 0; j < 4; j++) a += (double)xv0[j]*(double)wv0[j];
#pragma unroll
    for (int j = 0; j < 4; j++) a += (double)xv1[j]*(double)wv1[j];
#pragma unroll
    for (int s = 1; s < 64; s <<= 1) a += __shfl_xor(a, s);
    if ((t & 63) == 0) csum[t >> 6] = a;
    __syncthreads();
    if (t == 0){
      double tt = (csum[0] + csum[1]) + (csum[2] + csum[3]);
      float t32 = (float)tt;
      float u = x2b + w2sq[h];
      float d2 = u - 2.0f*t32;
      float d = __fsqrt_rn(fmaxf(d2, 1e-12f));
      if (d < bestd || (d == bestd && h < besti)){ bestd = d; besti = h; }
    }
    __syncthreads();
  }
  if (t == 0) winners[b] = (float)besti;

  float es = 0.f;
#pragma unroll
  for (int i = 0; i < 16; i++) es += __expf(-2.0f*(dv[i] - dmin));
#pragma unroll
  for (int s = 1; s < 64; s <<= 1) es += __shfl_xor(es, s);
  if ((t & 63) == 0) fred[t >> 6] = es;
  __syncthreads();
  const float tot = (fred[0] + fred[1]) + (fred[2] + fred[3]);
  const float inv = 1.0f / tot;
  ushort4* o4 = (ushort4*)(soft + (size_t)b*4096);
#pragma unroll
  for (int i = 0; i < 4; i++){
    ushort4 o;
    o.x = f2bf(__expf(-2.0f*(dv[i*4+0] - dmin))*inv);
    o.y = f2bf(__expf(-2.0f*(dv[i*4+1] - dmin))*inv);
    o.z = f2bf(__expf(-2.0f*(dv[i*4+2] - dmin))*inv);
    o.w = f2bf(__expf(-2.0f*(dv[i*4+3] - dmin))*inv);
    o4[t + 256*i] = o;
  }
}

extern "C" void kernel_launch(void* const* d_in, const int* in_sizes, int n_in,
                              void* d_out, int out_size, void* d_ws, size_t ws_size,
                              hipStream_t stream)
{
  const float* x  = (const float*)d_in[0];
  const float* Wk = (const float*)d_in[1];
  const float* w1 = (const float*)d_in[2];
  const float* b1 = (const float*)d_in[3];
  const float* w2 = (const float*)d_in[4];
  const float* b2 = (const float*)d_in[5];
  const float* w3 = (const float*)d_in[6];
  const float* b3 = (const float*)d_in[7];
  float* out = (float*)d_out;
  float* winners = out + (size_t)4096*1000;

  char* ws = (char*)d_ws;
  const size_t MB = 1u << 20;
  float* S   = (float*)(ws);              // 64MB  [dead after row_softmax]
  u16* xb    = (u16*)(ws + 64*MB);        // 16MB  [dead after gemm1]
  u16* wb    = (u16*)(ws + 80*MB);        // 16MB  [dead after gemm1]
  u16* soft  = (u16*)(ws + 64*MB);        // 32MB  overlays xb/wb
  u16* w1b   = (u16*)(ws + 96*MB);        // 16MB
  u16* w2b   = (u16*)(ws + 112*MB);       // 4MB
  u16* w3b   = (u16*)(ws + 116*MB);       // 2MB (padded 1024x1024)
  float* x2  = (float*)(ws + 118*MB);     // 16KB
  float* w2s = x2 + 4096;                 // 16KB
  u16* h1    = (u16*)(ws);                // 16MB overlays S
  u16* h2    = (u16*)(ws + 16*MB);        // 8MB  overlays S

  cvt_rows<<<4096, 64, 0, stream>>>(x, xb, x2);
  cvt_rows<<<4096, 64, 0, stream>>>(Wk, wb, w2s);
  cvt_mat<<<2048, 256, 0, stream>>>(w1, w1b, 2048*4096/4);
  cvt_mat<<<1024, 256, 0, stream>>>(w2, w2b, 1024*2048/4);
  hipMemsetAsync(w3b, 0, (size_t)1024*1024*2, stream);
  cvt_mat<<<512, 256, 0, stream>>>(w3, w3b, 1000*1024/4);

  // S = x @ W^T  (bf16 MFMA, fp32 acc)
  gemm_bt<0><<<dim3(32, 32), 256, 0, stream>>>(xb, wb, S, nullptr, nullptr,
                                               4096, 4096, 2048, 0);
  // distances -> winners (exact refine) + soft (bf16)
  row_softmax<<<4096, 256, 0, stream>>>(S, x2, w2s, x, Wk, soft, winners);
  // h1 = relu(soft @ w1^T + b1)
  gemm_bt<1><<<dim3(32, 16), 256, 0, stream>>>(soft, w1b, nullptr, h1, b1,
                                               4096, 2048, 4096, 0);
  // h2 = relu(h1 @ w2^T + b2)
  gemm_bt<1><<<dim3(32, 8), 256, 0, stream>>>(h1, w2b, nullptr, h2, b2,
                                              4096, 1024, 2048, 0);
  // out = h2 @ w3^T + b3  (fp32, 1000 valid cols)
  gemm_bt<2><<<dim3(32, 8), 256, 0, stream>>>(h2, w3b, out, nullptr, b3,
                                              4096, 1024, 1024, 1000);
}

// Round 2
// 288.250 us; speedup vs baseline: 1.2425x; 1.2425x over previous
//
#include <hip/hip_runtime.h>
#include <hip/hip_bf16.h>
#include <stdint.h>

typedef __attribute__((ext_vector_type(4))) float f32x4;
typedef __attribute__((ext_vector_type(8))) __bf16 bf16x8;
typedef unsigned short u16;
typedef unsigned long long u64;

__device__ __forceinline__ u16 f2bf(float f){
  unsigned u = __float_as_uint(f);
  u += 0x7fffu + ((u >> 16) & 1u);
  return (u16)(u >> 16);
}

__device__ __forceinline__ void gload16(const u16* g, u16* l){
  __builtin_amdgcn_global_load_lds(
      (__attribute__((address_space(1))) void*)g,
      (__attribute__((address_space(3))) void*)l, 16, 0, 0);
}

// ---- fp32 row matrix -> bf16 copy + numpy-pairwise row sum-of-squares ----
__global__ __launch_bounds__(64)
void cvt_rows(const float* __restrict__ src, u16* __restrict__ dst,
              float* __restrict__ sq)
{
#pragma clang fp contract(off)
  const int row = blockIdx.x;
  const int l = threadIdx.x;
  const float* r = src + (size_t)row * 2048;
  const f32x4* r4 = (const f32x4*)r;
  ushort4* d4 = (ushort4*)(dst + (size_t)row * 2048);
#pragma unroll
  for (int i = 0; i < 8; i++){
    f32x4 v = r4[l + 64*i];
    ushort4 o;
    o.x = f2bf(v.x); o.y = f2bf(v.y); o.z = f2bf(v.z); o.w = f2bf(v.w);
    d4[l + 64*i] = o;
  }
  float leaf = 0.f;
  if (l < 16){
    const float* p = r + l*128;
    float rr[8];
#pragma unroll
    for (int j = 0; j < 8; j++){ float v = p[j]; rr[j] = v*v; }
    for (int i = 8; i < 128; i += 8){
#pragma unroll
      for (int j = 0; j < 8; j++){ float v = p[i+j]; float vv = v*v; rr[j] = rr[j] + vv; }
    }
    leaf = ((rr[0]+rr[1])+(rr[2]+rr[3]))+((rr[4]+rr[5])+(rr[6]+rr[7]));
  }
#pragma unroll
  for (int s = 1; s < 16; s <<= 1){
    float o = __shfl_down(leaf, s);
    if ((l & (2*s - 1)) == 0) leaf = leaf + o;
  }
  if (l == 0) sq[row] = leaf;
}

// ---- generic fp32 -> bf16 elementwise ----
__global__ __launch_bounds__(256)
void cvt_mat(const float* __restrict__ src, u16* __restrict__ dst, int n4)
{
  const f32x4* s4 = (const f32x4*)src;
  ushort4* d4 = (ushort4*)dst;
  for (int i = blockIdx.x*256 + threadIdx.x; i < n4; i += gridDim.x*256){
    f32x4 v = s4[i];
    ushort4 o;
    o.x = f2bf(v.x); o.y = f2bf(v.y); o.z = f2bf(v.z); o.w = f2bf(v.w);
    d4[i] = o;
  }
}

// ---- deep-pipelined bf16 GEMM  C = A[M,K] * B[N,K]^T ----
// BK=32, 3 LDS K-tile buffers, counted vmcnt(4) (1 tile in flight), T2 swizzle,
// raw s_barrier phases + setprio around MFMA, XCD-bijective block swizzle.
// Race-free: stage K(t+2)->buf[(t+2)%3]; that buffer's last reads were in
// tile t-1, completed before the end-of-(t-1) barrier this wave crossed.
// EPI 0: fp32 C (ldc=N).  EPI 1: relu(C+bias)->bf16 (ldc=N).
// EPI 2: C+bias->fp32 packed ldc=ncols, guard col<ncols.
template<int BM, int BN, int WM, int WN, int EPI>
__global__ __launch_bounds__(WM*WN*64, 2)
void gemm_p(const u16* __restrict__ A, const u16* __restrict__ Bm,
            float* __restrict__ Cf, u16* __restrict__ Cb,
            const float* __restrict__ bias,
            int M, int N, int K, int ncols, int nbn)
{
  constexpr int T  = WM*WN*64;
  constexpr int FM = BM/(WM*16);
  constexpr int FN = BN/(WN*16);
  constexpr int ABYTES = BM*64;            // bytes per A K-tile (BK=32 bf16)
  constexpr int BUFB   = (BM+BN)*64;       // bytes per buffer (A then B)
  constexpr int RA = ABYTES/(T*16);        // stage rounds (=2)
  constexpr int RB = (BN*64)/(T*16);
  extern __shared__ char lds[];

  const int t = threadIdx.x;
  const int nwg = gridDim.x;
  const int cpx = nwg >> 3;
  const int bid = blockIdx.x;
  const int wg  = (bid & 7)*cpx + (bid >> 3);   // XCD swizzle (nwg%8==0)
  const int bm = wg / nbn, bn = wg % nbn;
  const int brow = bm*BM, bcol = bn*BN;

  const int l = t & 63, w = t >> 6;
  const int wm = w / WN, wn = w % WN;
  const int wr = wm*(FM*16), wc = wn*(FN*16);
  const int fr = l & 15, fk = (l >> 4)*8;
  const int xk = fk ^ ((fr & 12) << 1);         // T2 swizzled k-col (u16)

  const int srow = t >> 2;                      // staging row within round
  const int scol = (t & 3)*8;                   // u16 col (pre-swizzle)

  // precomputed, inverse-swizzled global staging bases (rule #21)
  const u16* agp[RA]; const u16* bgp[RB];
#pragma unroll
  for (int r = 0; r < RA; r++){
    const int row = r*(T>>2) + srow;
    agp[r] = A + (size_t)(brow + row)*K + (scol ^ ((row & 12) << 1));
  }
#pragma unroll
  for (int r = 0; r < RB; r++){
    const int row = r*(T>>2) + srow;
    bgp[r] = Bm + (size_t)(bcol + row)*K + (scol ^ ((row & 12) << 1));
  }

  f32x4 acc[FM][FN] = {};
  const int nt = K >> 5;

  auto stageA = [&](int kt, int buf){
    char* dst = lds + buf*BUFB + t*16;
#pragma unroll
    for (int r = 0; r < RA; r++)
      gload16(agp[r] + (kt << 5), (u16*)(dst + r*T*16));
  };
  auto stageB = [&](int kt, int buf){
    char* dst = lds + buf*BUFB + ABYTES + t*16;
#pragma unroll
    for (int r = 0; r < RB; r++)
      gload16(bgp[r] + (kt << 5), (u16*)(dst + r*T*16));
  };

  // prologue: K0 -> buf0, K1 -> buf1; wait K0 (4 of 8 loads), barrier
  stageA(0, 0); stageB(0, 0);
  stageA(1, 1); stageB(1, 1);
  asm volatile("s_waitcnt vmcnt(4)" ::: "memory");
  __builtin_amdgcn_s_barrier();

  for (int kt = 0; kt < nt; kt++){
    const int buf = kt % 3;
    const u16* As = (const u16*)(lds + buf*BUFB);
    const u16* Bs = (const u16*)(lds + buf*BUFB + ABYTES);
    const bool pre = (kt + 2 < nt);
    const int nbuf = (kt + 2) % 3;

    bf16x8 av[FM], bv[FN];
#pragma unroll
    for (int m = 0; m < FM; m++)
      av[m] = *(const bf16x8*)(As + (wr + m*16 + fr)*32 + xk);
#pragma unroll
    for (int n = 0; n < FN/2; n++)
      bv[n] = *(const bf16x8*)(Bs + (wc + n*16 + fr)*32 + xk);
    if (pre) stageA(kt + 2, nbuf);
    __builtin_amdgcn_s_barrier();
    __builtin_amdgcn_s_setprio(1);
#pragma unroll
    for (int m = 0; m < FM; m++)
#pragma unroll
      for (int n = 0; n < FN/2; n++)
        acc[m][n] = __builtin_amdgcn_mfma_f32_16x16x32_bf16(av[m], bv[n], acc[m][n], 0, 0, 0);
    __builtin_amdgcn_s_setprio(0);

#pragma unroll
    for (int n = FN/2; n < FN; n++)
      bv[n] = *(const bf16x8*)(Bs + (wc + n*16 + fr)*32 + xk);
    if (pre) stageB(kt + 2, nbuf);
    __builtin_amdgcn_s_barrier();
    __builtin_amdgcn_s_setprio(1);
#pragma unroll
    for (int m = 0; m < FM; m++)
#pragma unroll
      for (int n = FN/2; n < FN; n++)
        acc[m][n] = __builtin_amdgcn_mfma_f32_16x16x32_bf16(av[m], bv[n], acc[m][n], 0, 0, 0);
    __builtin_amdgcn_s_setprio(0);

    if (kt + 1 < nt){
      if (pre) asm volatile("s_waitcnt vmcnt(4)" ::: "memory");
      else     asm volatile("s_waitcnt vmcnt(0)" ::: "memory");
      __builtin_amdgcn_s_barrier();
    }
  }

#pragma unroll
  for (int n = 0; n < FN; n++){
    const int gcol = bcol + wc + n*16 + fr;
    float bvv = 0.f;
    if (EPI == 1) bvv = bias[gcol];
    if (EPI == 2 && gcol < ncols) bvv = bias[gcol];
#pragma unroll
    for (int m = 0; m < FM; m++){
      const int grow = brow + wr + m*16 + (l >> 4)*4;
#pragma unroll
      for (int r = 0; r < 4; r++){
        float v = acc[m][n][r];
        if (EPI == 0){
          Cf[(size_t)(grow + r)*N + gcol] = v;
        } else if (EPI == 1){
          Cb[(size_t)(grow + r)*N + gcol] = f2bf(fmaxf(v + bvv, 0.f));
        } else {
          if (gcol < ncols) Cf[(size_t)(grow + r)*ncols + gcol] = v + bvv;
        }
      }
    }
  }
}

// ---- per-row: distances, argmin (exact fp64-refined candidates), softmax ----
__global__ __launch_bounds__(256)
void row_softmax(const float* __restrict__ S, const float* __restrict__ x2,
                 const float* __restrict__ w2sq,
                 const float* __restrict__ x, const float* __restrict__ W,
                 u16* __restrict__ soft, float* __restrict__ winners)
{
  const int b = blockIdx.x, t = threadIdx.x;
  const float x2b = x2[b];
  const f32x4* S4 = (const f32x4*)(S + (size_t)b*4096);
  const f32x4* W24 = (const f32x4*)w2sq;
  float dv[16];
  float bd = 3.0e38f; int bc = 0;
#pragma unroll
  for (int i = 0; i < 4; i++){
    f32x4 s = S4[t + 256*i];
    f32x4 wv = W24[t + 256*i];
#pragma unroll
    for (int j = 0; j < 4; j++){
      float u = x2b + wv[j];
      float d2 = u - 2.0f*s[j];
      float d = __fsqrt_rn(fmaxf(d2, 1e-12f));
      dv[i*4 + j] = d;
      if (d < bd){ bd = d; bc = (t + 256*i)*4 + j; }
    }
  }
  u64 key = ((u64)__float_as_uint(bd) << 32) | (unsigned)bc;
#pragma unroll
  for (int s = 1; s < 64; s <<= 1){
    u64 o = __shfl_xor(key, s);
    if (o < key) key = o;
  }
  __shared__ u64 wk[4];
  __shared__ double csum[4];
  __shared__ float fred[4];
  __shared__ int ccnt;
  __shared__ int cand[32];
  if ((t & 63) == 0) wk[t >> 6] = key;
  if (t == 0) ccnt = 0;
  __syncthreads();
  u64 k0 = wk[0];
  if (wk[1] < k0) k0 = wk[1];
  if (wk[2] < k0) k0 = wk[2];
  if (wk[3] < k0) k0 = wk[3];
  const float dmin = __uint_as_float((unsigned)(k0 >> 32));

  const float thr = dmin + 0.01f;   // >100 sigma of bf16-GEMM noise on d
#pragma unroll
  for (int i = 0; i < 4; i++)
#pragma unroll
    for (int j = 0; j < 4; j++)
      if (dv[i*4 + j] <= thr){
        int p = atomicAdd(&ccnt, 1);
        if (p < 32) cand[p] = (t + 256*i)*4 + j;
      }
  __syncthreads();
  const int nc = min(ccnt, 32);

  float bestd = 3.0e38f; int besti = 0x7fffffff;
  const f32x4* xp = (const f32x4*)(x + (size_t)b*2048) + t*2;
  f32x4 xv0 = xp[0], xv1 = xp[1];
  for (int c = 0; c < nc; c++){
    const int h = cand[c];
    const f32x4* wp = (const f32x4*)(W + (size_t)h*2048) + t*2;
    f32x4 wv0 = wp[0], wv1 = wp[1];
    double a = 0.0;
#pragma unroll
    for (int j = 0; j < 4; j++) a += (double)xv0[j]*(double)wv0[j];
#pragma unroll
    for (int j = 0; j < 4; j++) a += (double)xv1[j]*(double)wv1[j];
#pragma unroll
    for (int s = 1; s < 64; s <<= 1) a += __shfl_xor(a, s);
    if ((t & 63) == 0) csum[t >> 6] = a;
    __syncthreads();
    if (t == 0){
      double tt = (csum[0] + csum[1]) + (csum[2] + csum[3]);
      float t32 = (float)tt;
      float u = x2b + w2sq[h];
      float d2 = u - 2.0f*t32;
      float d = __fsqrt_rn(fmaxf(d2, 1e-12f));
      if (d < bestd || (d == bestd && h < besti)){ bestd = d; besti = h; }
    }
    __syncthreads();
  }
  if (t == 0) winners[b] = (float)besti;

  float es = 0.f;
#pragma unroll
  for (int i = 0; i < 16; i++) es += __expf(-2.0f*(dv[i] - dmin));
#pragma unroll
  for (int s = 1; s < 64; s <<= 1) es += __shfl_xor(es, s);
  if ((t & 63) == 0) fred[t >> 6] = es;
  __syncthreads();
  const float tot = (fred[0] + fred[1]) + (fred[2] + fred[3]);
  const float inv = 1.0f / tot;
  ushort4* o4 = (ushort4*)(soft + (size_t)b*4096);
#pragma unroll
  for (int i = 0; i < 4; i++){
    ushort4 o;
    o.x = f2bf(__expf(-2.0f*(dv[i*4+0] - dmin))*inv);
    o.y = f2bf(__expf(-2.0f*(dv[i*4+1] - dmin))*inv);
    o.z = f2bf(__expf(-2.0f*(dv[i*4+2] - dmin))*inv);
    o.w = f2bf(__expf(-2.0f*(dv[i*4+3] - dmin))*inv);
    o4[t + 256*i] = o;
  }
}

extern "C" void kernel_launch(void* const* d_in, const int* in_sizes, int n_in,
                              void* d_out, int out_size, void* d_ws, size_t ws_size,
                              hipStream_t stream)
{
  const float* x  = (const float*)d_in[0];
  const float* Wk = (const float*)d_in[1];
  const float* w1 = (const float*)d_in[2];
  const float* b1 = (const float*)d_in[3];
  const float* w2 = (const float*)d_in[4];
  const float* b2 = (const float*)d_in[5];
  const float* w3 = (const float*)d_in[6];
  const float* b3 = (const float*)d_in[7];
  float* out = (float*)d_out;
  float* winners = out + (size_t)4096*1000;

  char* ws = (char*)d_ws;
  const size_t MB = 1u << 20;
  float* S   = (float*)(ws);              // 64MB  [dead after row_softmax]
  u16* xb    = (u16*)(ws + 64*MB);        // 16MB  [dead after gemm1]
  u16* wb    = (u16*)(ws + 80*MB);        // 16MB  [dead after gemm1]
  u16* soft  = (u16*)(ws + 64*MB);        // 32MB  overlays xb/wb
  u16* w1b   = (u16*)(ws + 96*MB);        // 16MB
  u16* w2b   = (u16*)(ws + 112*MB);       // 4MB
  u16* w3b   = (u16*)(ws + 116*MB);       // 2MB (padded 1024x1024)
  float* x2  = (float*)(ws + 118*MB);     // 16KB
  float* w2s = x2 + 4096;                 // 16KB
  u16* h1    = (u16*)(ws);                // 16MB overlays S
  u16* h2    = (u16*)(ws + 16*MB);        // 8MB  overlays S

  cvt_rows<<<4096, 64, 0, stream>>>(x, xb, x2);
  cvt_rows<<<4096, 64, 0, stream>>>(Wk, wb, w2s);
  cvt_mat<<<2048, 256, 0, stream>>>(w1, w1b, 2048*4096/4);
  cvt_mat<<<1024, 256, 0, stream>>>(w2, w2b, 1024*2048/4);
  hipMemsetAsync(w3b, 0, (size_t)1024*1024*2, stream);
  cvt_mat<<<512, 256, 0, stream>>>(w3, w3b, 1000*1024/4);

  // S = x @ W^T  (256^2 tile, 8 waves, 96KB LDS deep pipe)
  hipFuncSetAttribute((const void*)gemm_p<256,256,2,4,0>,
                      hipFuncAttributeMaxDynamicSharedMemorySize, 3*512*64);
  gemm_p<256,256,2,4,0><<<256, 512, 3*512*64, stream>>>(
      xb, wb, S, nullptr, nullptr, 4096, 4096, 2048, 0, 16);

  // distances -> winners (exact refine) + soft (bf16)
  row_softmax<<<4096, 256, 0, stream>>>(S, x2, w2s, x, Wk, soft, winners);

  // h1 = relu(soft @ w1^T + b1)   (128^2 tile, 512 blocks)
  gemm_p<128,128,2,2,1><<<512, 256, 3*256*64, stream>>>(
      soft, w1b, nullptr, h1, b1, 4096, 2048, 4096, 0, 16);
  // h2 = relu(h1 @ w2^T + b2)
  gemm_p<128,128,2,2,1><<<256, 256, 3*256*64, stream>>>(
      h1, w2b, nullptr, h2, b2, 4096, 1024, 2048, 0, 8);
  // out = h2 @ w3^T + b3  (fp32, 1000 valid cols)
  gemm_p<128,128,2,2,2><<<256, 256, 3*256*64, stream>>>(
      h2, w3b, out, nullptr, b3, 4096, 1024, 1024, 1000, 8);
}

// Round 3
// 274.778 us; speedup vs baseline: 1.3034x; 1.0490x over previous
//
#include <hip/hip_runtime.h>
#include <hip/hip_bf16.h>
#include <stdint.h>

typedef __attribute__((ext_vector_type(4))) float f32x4;
typedef __attribute__((ext_vector_type(8))) __bf16 bf16x8;
typedef unsigned short u16;
typedef unsigned long long u64;

__device__ __forceinline__ u16 f2bf(float f){
  unsigned u = __float_as_uint(f);
  u += 0x7fffu + ((u >> 16) & 1u);
  return (u16)(u >> 16);
}
__device__ __forceinline__ float bf2f(u16 v){
  return __uint_as_float(((unsigned)v) << 16);
}

__device__ __forceinline__ void gload16(const u16* g, u16* l){
  __builtin_amdgcn_global_load_lds(
      (__attribute__((address_space(1))) void*)g,
      (__attribute__((address_space(3))) void*)l, 16, 0, 0);
}

template<int N> __device__ __forceinline__ void waitcnt_vm(){
  if constexpr (N==0) asm volatile("s_waitcnt vmcnt(0)" ::: "memory");
  else if constexpr (N==2) asm volatile("s_waitcnt vmcnt(2)" ::: "memory");
  else if constexpr (N==3) asm volatile("s_waitcnt vmcnt(3)" ::: "memory");
  else if constexpr (N==4) asm volatile("s_waitcnt vmcnt(4)" ::: "memory");
  else if constexpr (N==6) asm volatile("s_waitcnt vmcnt(6)" ::: "memory");
}

// ---- fp32 row matrix -> bf16 copy + numpy-pairwise row sum-of-squares ----
// numpy pairwise_sum(n=2048): 16 leaves of 128 (8-accumulator unrolled loop,
// ((r0+r1)+(r2+r3))+((r4+r5)+(r6+r7))), balanced binary combine tree.
// Vector form: acc0[j] == rr[j], acc1[j] == rr[4+j] -- identical FP order.
__global__ __launch_bounds__(64)
void cvt_rows(const float* __restrict__ src, u16* __restrict__ dst,
              float* __restrict__ sq)
{
#pragma clang fp contract(off)
  const int row = blockIdx.x;
  const int l = threadIdx.x;
  const float* r = src + (size_t)row * 2048;
  const f32x4* r4 = (const f32x4*)r;
  ushort4* d4 = (ushort4*)(dst + (size_t)row * 2048);
#pragma unroll
  for (int i = 0; i < 8; i++){
    f32x4 v = r4[l + 64*i];
    ushort4 o;
    o.x = f2bf(v.x); o.y = f2bf(v.y); o.z = f2bf(v.z); o.w = f2bf(v.w);
    d4[l + 64*i] = o;
  }
  float leaf = 0.f;
  if (l < 16){
    const f32x4* p4 = (const f32x4*)(r + l*128);
    f32x4 a0 = {0.f,0.f,0.f,0.f}, a1 = {0.f,0.f,0.f,0.f};
#pragma unroll
    for (int i = 0; i < 32; i += 2){
      f32x4 v0 = p4[i], v1 = p4[i+1];
      a0 = a0 + v0*v0;
      a1 = a1 + v1*v1;
    }
    leaf = ((a0.x+a0.y)+(a0.z+a0.w))+((a1.x+a1.y)+(a1.z+a1.w));
  }
#pragma unroll
  for (int s = 1; s < 16; s <<= 1){
    float o = __shfl_down(leaf, s);
    if ((l & (2*s - 1)) == 0) leaf = leaf + o;
  }
  if (l == 0) sq[row] = leaf;
}

// ---- generic fp32 -> bf16 elementwise ----
__global__ __launch_bounds__(256)
void cvt_mat(const float* __restrict__ src, u16* __restrict__ dst, int n4)
{
  const f32x4* s4 = (const f32x4*)src;
  ushort4* d4 = (ushort4*)dst;
  for (int i = blockIdx.x*256 + threadIdx.x; i < n4; i += gridDim.x*256){
    f32x4 v = s4[i];
    ushort4 o;
    o.x = f2bf(v.x); o.y = f2bf(v.y); o.z = f2bf(v.z); o.w = f2bf(v.w);
    d4[i] = o;
  }
}

// ---- deep-pipelined bf16 GEMM  C = A[M,K] * B[N,K]^T ----
// BK=32, 3 LDS K-tile buffers, counted vmcnt (never 0 mid-loop), conflict-free
// XOR swizzle chunk' = chunk ^ ((row>>1)&3)  [stage-source pre-swizzled so
// global_load_lds stays linear -- rule #21], setprio around MFMA, XCD swizzle.
// Race-free: stage K(t+2)->buf[(t+2)%3]=buf[(t-1)%3]; all waves finished
// reading that buffer before the end-of-(t-1) barrier this wave has crossed.
// EPI 0: fp32 C.  EPI 1: relu(C+bias)->bf16.  EPI 2: C+bias fp32 packed
// ldc=ncols guard col<ncols.  EPI 3: plain bf16 C.
template<int BM, int BN, int WM, int WN, int EPI, int MINW>
__global__ __launch_bounds__(WM*WN*64, MINW)
void gemm_p(const u16* __restrict__ A, const u16* __restrict__ Bm,
            float* __restrict__ Cf, u16* __restrict__ Cb,
            const float* __restrict__ bias,
            int M, int N, int K, int ncols, int nbn)
{
  constexpr int T  = WM*WN*64;
  constexpr int FM = BM/(WM*16);
  constexpr int FN = BN/(WN*16);
  constexpr int ABYTES = BM*64;            // bytes per A K-tile (BK=32 bf16)
  constexpr int BUFB   = (BM+BN)*64;       // bytes per buffer (A then B)
  constexpr int RA = ABYTES/(T*16);        // stage rounds for A
  constexpr int RB = (BN*64)/(T*16);       // stage rounds for B
  constexpr int IF = RA + RB;              // loads in flight per K-tile
  constexpr int NPH = (FM*FN >= 32) ? 2 : 1;
  extern __shared__ char lds[];

  const int t = threadIdx.x;
  const int nwg = gridDim.x;
  const int cpx = nwg >> 3;
  const int bid = blockIdx.x;
  const int wg  = (bid & 7)*cpx + (bid >> 3);   // XCD swizzle (nwg%8==0)
  const int bm = wg / nbn, bn = wg % nbn;
  const int brow = bm*BM, bcol = bn*BN;

  const int l = t & 63, w = t >> 6;
  const int wm = w / WN, wn = w % WN;
  const int wr = wm*(FM*16), wc = wn*(FN*16);
  const int fr = l & 15, fk = (l >> 4)*8;
  const int xk = fk ^ (((fr >> 1) & 3) << 3);   // conflict-free read col (u16)

  const int srow = t >> 2;                      // staging row within round
  const int scol = ((t & 3)*8) ^ (((t >> 3) & 3) << 3); // inverse-swz source

  const u16* agp[RA]; const u16* bgp[RB];
#pragma unroll
  for (int r = 0; r < RA; r++)
    agp[r] = A + (size_t)(brow + r*(T>>2) + srow)*K + scol;
#pragma unroll
  for (int r = 0; r < RB; r++)
    bgp[r] = Bm + (size_t)(bcol + r*(T>>2) + srow)*K + scol;

  f32x4 acc[FM][FN] = {};
  const int nt = K >> 5;

  auto stageA = [&](int kt, int buf){
    char* dst = lds + buf*BUFB + t*16;
#pragma unroll
    for (int r = 0; r < RA; r++)
      gload16(agp[r] + (kt << 5), (u16*)(dst + r*T*16));
  };
  auto stageB = [&](int kt, int buf){
    char* dst = lds + buf*BUFB + ABYTES + t*16;
#pragma unroll
    for (int r = 0; r < RB; r++)
      gload16(bgp[r] + (kt << 5), (u16*)(dst + r*T*16));
  };

  // prologue: K0 -> buf0, K1 -> buf1; wait K0, barrier
  stageA(0, 0); stageB(0, 0);
  stageA(1, 1); stageB(1, 1);
  waitcnt_vm<IF>();
  __builtin_amdgcn_s_barrier();

  for (int kt = 0; kt < nt; kt++){
    const int buf = kt % 3;
    const u16* As = (const u16*)(lds + buf*BUFB);
    const u16* Bs = (const u16*)(lds + buf*BUFB + ABYTES);
    const bool pre = (kt + 2 < nt);
    const int nbuf = (kt + 2) % 3;

    bf16x8 av[FM], bv[FN];
#pragma unroll
    for (int m = 0; m < FM; m++)
      av[m] = *(const bf16x8*)(As + (wr + m*16 + fr)*32 + xk);

    if (NPH == 1){
#pragma unroll
      for (int n = 0; n < FN; n++)
        bv[n] = *(const bf16x8*)(Bs + (wc + n*16 + fr)*32 + xk);
      if (pre){ stageA(kt + 2, nbuf); stageB(kt + 2, nbuf); }
      __builtin_amdgcn_s_barrier();
      __builtin_amdgcn_s_setprio(1);
#pragma unroll
      for (int m = 0; m < FM; m++)
#pragma unroll
        for (int n = 0; n < FN; n++)
          acc[m][n] = __builtin_amdgcn_mfma_f32_16x16x32_bf16(av[m], bv[n], acc[m][n], 0, 0, 0);
      __builtin_amdgcn_s_setprio(0);
    } else {
#pragma unroll
      for (int n = 0; n < FN/2; n++)
        bv[n] = *(const bf16x8*)(Bs + (wc + n*16 + fr)*32 + xk);
      if (pre) stageA(kt + 2, nbuf);
      __builtin_amdgcn_s_barrier();
      __builtin_amdgcn_s_setprio(1);
#pragma unroll
      for (int m = 0; m < FM; m++)
#pragma unroll
        for (int n = 0; n < FN/2; n++)
          acc[m][n] = __builtin_amdgcn_mfma_f32_16x16x32_bf16(av[m], bv[n], acc[m][n], 0, 0, 0);
      __builtin_amdgcn_s_setprio(0);

#pragma unroll
      for (int n = FN/2; n < FN; n++)
        bv[n] = *(const bf16x8*)(Bs + (wc + n*16 + fr)*32 + xk);
      if (pre) stageB(kt + 2, nbuf);
      __builtin_amdgcn_s_barrier();
      __builtin_amdgcn_s_setprio(1);
#pragma unroll
      for (int m = 0; m < FM; m++)
#pragma unroll
        for (int n = FN/2; n < FN; n++)
          acc[m][n] = __builtin_amdgcn_mfma_f32_16x16x32_bf16(av[m], bv[n], acc[m][n], 0, 0, 0);
      __builtin_amdgcn_s_setprio(0);
    }

    if (kt + 1 < nt){
      if (pre) waitcnt_vm<IF>();
      else     waitcnt_vm<0>();
      __builtin_amdgcn_s_barrier();
    }
  }

#pragma unroll
  for (int n = 0; n < FN; n++){
    const int gcol = bcol + wc + n*16 + fr;
    float bvv = 0.f;
    if (EPI == 1) bvv = bias[gcol];
    if (EPI == 2 && gcol < ncols) bvv = bias[gcol];
#pragma unroll
    for (int m = 0; m < FM; m++){
      const int grow = brow + wr + m*16 + (l >> 4)*4;
#pragma unroll
      for (int r = 0; r < 4; r++){
        float v = acc[m][n][r];
        if (EPI == 0){
          Cf[(size_t)(grow + r)*N + gcol] = v;
        } else if (EPI == 1){
          Cb[(size_t)(grow + r)*N + gcol] = f2bf(fmaxf(v + bvv, 0.f));
        } else if (EPI == 2){
          if (gcol < ncols) Cf[(size_t)(grow + r)*ncols + gcol] = v + bvv;
        } else {
          Cb[(size_t)(grow + r)*N + gcol] = f2bf(v);
        }
      }
    }
  }
}

// ---- per-row: distances, argmin (exact fp64-refined candidates), softmax ----
__global__ __launch_bounds__(256)
void row_softmax(const u16* __restrict__ Sb, const float* __restrict__ x2,
                 const float* __restrict__ w2sq,
                 const float* __restrict__ x, const float* __restrict__ W,
                 u16* __restrict__ soft, float* __restrict__ winners)
{
  const int b = blockIdx.x, t = threadIdx.x;
  const float x2b = x2[b];
  const ushort4* S4 = (const ushort4*)(Sb + (size_t)b*4096);
  const f32x4* W24 = (const f32x4*)w2sq;
  float dv[16];
  float bd = 3.0e38f; int bc = 0;
#pragma unroll
  for (int i = 0; i < 4; i++){
    ushort4 s = S4[t + 256*i];
    f32x4 wv = W24[t + 256*i];
    float sf[4] = {bf2f(s.x), bf2f(s.y), bf2f(s.z), bf2f(s.w)};
#pragma unroll
    for (int j = 0; j < 4; j++){
      float u = x2b + wv[j];
      float d2 = u - 2.0f*sf[j];
      float d = __fsqrt_rn(fmaxf(d2, 1e-12f));
      dv[i*4 + j] = d;
      if (d < bd){ bd = d; bc = (t + 256*i)*4 + j; }
    }
  }
  u64 key = ((u64)__float_as_uint(bd) << 32) | (unsigned)bc;
#pragma unroll
  for (int s = 1; s < 64; s <<= 1){
    u64 o = __shfl_xor(key, s);
    if (o < key) key = o;
  }
  __shared__ u64 wk[4];
  __shared__ double csum[4];
  __shared__ float fred[4];
  __shared__ int ccnt;
  __shared__ int cand[32];
  if ((t & 63) == 0) wk[t >> 6] = key;
  if (t == 0) ccnt = 0;
  __syncthreads();
  u64 k0 = wk[0];
  if (wk[1] < k0) k0 = wk[1];
  if (wk[2] < k0) k0 = wk[2];
  if (wk[3] < k0) k0 = wk[3];
  const float dmin = __uint_as_float((unsigned)(k0 >> 32));

  const float thr = dmin + 0.01f;   // >>20 sigma of bf16 GEMM+storage noise
#pragma unroll
  for (int i = 0; i < 4; i++)
#pragma unroll
    for (int j = 0; j < 4; j++)
      if (dv[i*4 + j] <= thr){
        int p = atomicAdd(&ccnt, 1);
        if (p < 32) cand[p] = (t + 256*i)*4 + j;
      }
  __syncthreads();
  const int nc = min(ccnt, 32);

  float bestd = 3.0e38f; int besti = 0x7fffffff;
  const f32x4* xp = (const f32x4*)(x + (size_t)b*2048) + t*2;
  f32x4 xv0 = xp[0], xv1 = xp[1];
  for (int c = 0; c < nc; c++){
    const int h = cand[c];
    const f32x4* wp = (const f32x4*)(W + (size_t)h*2048) + t*2;
    f32x4 wv0 = wp[0], wv1 = wp[1];
    double a = 0.0;
#pragma unroll
    for (int j = 0; j < 4; j++) a += (double)xv0[j]*(double)wv0[j];
#pragma unroll
    for (int j = 0; j < 4; j++) a += (double)xv1[j]*(double)wv1[j];
#pragma unroll
    for (int s = 1; s < 64; s <<= 1) a += __shfl_xor(a, s);
    if ((t & 63) == 0) csum[t >> 6] = a;
    __syncthreads();
    if (t == 0){
      double tt = (csum[0] + csum[1]) + (csum[2] + csum[3]);
      float t32 = (float)tt;
      float u = x2b + w2sq[h];
      float d2 = u - 2.0f*t32;
      float d = __fsqrt_rn(fmaxf(d2, 1e-12f));
      if (d < bestd || (d == bestd && h < besti)){ bestd = d; besti = h; }
    }
    __syncthreads();
  }
  if (t == 0) winners[b] = (float)besti;

  float es = 0.f;
#pragma unroll
  for (int i = 0; i < 16; i++) es += __expf(-2.0f*(dv[i] - dmin));
#pragma unroll
  for (int s = 1; s < 64; s <<= 1) es += __shfl_xor(es, s);
  if ((t & 63) == 0) fred[t >> 6] = es;
  __syncthreads();
  const float tot = (fred[0] + fred[1]) + (fred[2] + fred[3]);
  const float inv = 1.0f / tot;
  ushort4* o4 = (ushort4*)(soft + (size_t)b*4096);
#pragma unroll
  for (int i = 0; i < 4; i++){
    ushort4 o;
    o.x = f2bf(__expf(-2.0f*(dv[i*4+0] - dmin))*inv);
    o.y = f2bf(__expf(-2.0f*(dv[i*4+1] - dmin))*inv);
    o.z = f2bf(__expf(-2.0f*(dv[i*4+2] - dmin))*inv);
    o.w = f2bf(__expf(-2.0f*(dv[i*4+3] - dmin))*inv);
    o4[t + 256*i] = o;
  }
}

extern "C" void kernel_launch(void* const* d_in, const int* in_sizes, int n_in,
                              void* d_out, int out_size, void* d_ws, size_t ws_size,
                              hipStream_t stream)
{
  const float* x  = (const float*)d_in[0];
  const float* Wk = (const float*)d_in[1];
  const float* w1 = (const float*)d_in[2];
  const float* b1 = (const float*)d_in[3];
  const float* w2 = (const float*)d_in[4];
  const float* b2 = (const float*)d_in[5];
  const float* w3 = (const float*)d_in[6];
  const float* b3 = (const float*)d_in[7];
  float* out = (float*)d_out;
  float* winners = out + (size_t)4096*1000;

  char* ws = (char*)d_ws;
  const size_t MB = 1u << 20;
  u16* Sb    = (u16*)(ws);                // 32MB bf16 S [dead after row_softmax]
  u16* xb    = (u16*)(ws + 32*MB);        // 16MB [dead after gemm1]
  u16* wb    = (u16*)(ws + 48*MB);        // 16MB [dead after gemm1]
  u16* soft  = (u16*)(ws + 32*MB);        // 32MB overlays xb/wb
  u16* w1b   = (u16*)(ws + 64*MB);        // 16MB
  u16* w2b   = (u16*)(ws + 80*MB);        // 4MB
  u16* w3b   = (u16*)(ws + 84*MB);        // 2MB (padded 1024x1024)
  float* x2  = (float*)(ws + 86*MB);      // 16KB
  float* w2s = x2 + 4096;                 // 16KB
  u16* h1    = (u16*)(ws);                // 16MB overlays Sb
  u16* h2    = (u16*)(ws + 16*MB);        // 8MB  overlays Sb

  cvt_rows<<<4096, 64, 0, stream>>>(x, xb, x2);
  cvt_rows<<<4096, 64, 0, stream>>>(Wk, wb, w2s);
  cvt_mat<<<2048, 256, 0, stream>>>(w1, w1b, 2048*4096/4);
  cvt_mat<<<1024, 256, 0, stream>>>(w2, w2b, 1024*2048/4);
  hipMemsetAsync(w3b, 0, (size_t)1024*1024*2, stream);
  cvt_mat<<<512, 256, 0, stream>>>(w3, w3b, 1000*1024/4);

  // S = x @ W^T  -> bf16 (256^2 tile, 8 waves, 96KB LDS deep pipe)
  hipFuncSetAttribute((const void*)gemm_p<256,256,2,4,3,2>,
                      hipFuncAttributeMaxDynamicSharedMemorySize, 3*512*64);
  gemm_p<256,256,2,4,3,2><<<256, 512, 3*512*64, stream>>>(
      xb, wb, nullptr, Sb, nullptr, 4096, 4096, 2048, 0, 16);

  // distances -> winners (exact refine) + soft (bf16)
  row_softmax<<<4096, 256, 0, stream>>>(Sb, x2, w2s, x, Wk, soft, winners);

  // h1 = relu(soft @ w1^T + b1)   (256x128 tile, 8 waves of 64x64)
  hipFuncSetAttribute((const void*)gemm_p<256,128,4,2,1,2>,
                      hipFuncAttributeMaxDynamicSharedMemorySize, 3*384*64);
  gemm_p<256,128,4,2,1,2><<<256, 512, 3*384*64, stream>>>(
      soft, w1b, nullptr, h1, b1, 4096, 2048, 4096, 0, 16);

  // h2 = relu(h1 @ w2^T + b2)   (128^2 tile, 4 waves of 64x64, 3 blocks/CU)
  hipFuncSetAttribute((const void*)gemm_p<128,128,2,2,1,3>,
                      hipFuncAttributeMaxDynamicSharedMemorySize, 3*256*64);
  gemm_p<128,128,2,2,1,3><<<256, 256, 3*256*64, stream>>>(
      h1, w2b, nullptr, h2, b2, 4096, 1024, 2048, 0, 8);

  // out = h2 @ w3^T + b3  (fp32, 1000 valid cols)
  hipFuncSetAttribute((const void*)gemm_p<128,128,2,2,2,3>,
                      hipFuncAttributeMaxDynamicSharedMemorySize, 3*256*64);
  gemm_p<128,128,2,2,2,3><<<256, 256, 3*256*64, stream>>>(
      h2, w3b, out, nullptr, b3, 4096, 1024, 1024, 1000, 8);
}

// Round 4
// 268.641 us; speedup vs baseline: 1.3332x; 1.0228x over previous
//
#include <hip/hip_runtime.h>
#include <hip/hip_bf16.h>
#include <stdint.h>

typedef __attribute__((ext_vector_type(4))) float f32x4;
typedef __attribute__((ext_vector_type(8))) __bf16 bf16x8;
typedef unsigned short u16;
typedef unsigned long long u64;

__device__ __forceinline__ u16 f2bf(float f){
  unsigned u = __float_as_uint(f);
  u += 0x7fffu + ((u >> 16) & 1u);
  return (u16)(u >> 16);
}
__device__ __forceinline__ float bf2f(u16 v){
  return __uint_as_float(((unsigned)v) << 16);
}

__device__ __forceinline__ void gload16(const u16* g, u16* l){
  __builtin_amdgcn_global_load_lds(
      (__attribute__((address_space(1))) void*)g,
      (__attribute__((address_space(3))) void*)l, 16, 0, 0);
}

template<int N> __device__ __forceinline__ void waitcnt_vm(){
  if constexpr (N==0) asm volatile("s_waitcnt vmcnt(0)" ::: "memory");
  else if constexpr (N==2) asm volatile("s_waitcnt vmcnt(2)" ::: "memory");
  else if constexpr (N==3) asm volatile("s_waitcnt vmcnt(3)" ::: "memory");
  else if constexpr (N==4) asm volatile("s_waitcnt vmcnt(4)" ::: "memory");
  else if constexpr (N==6) asm volatile("s_waitcnt vmcnt(6)" ::: "memory");
  else if constexpr (N==8) asm volatile("s_waitcnt vmcnt(8)" ::: "memory");
}

// ---- fp32 row matrix -> bf16 copy + numpy-pairwise row sum-of-squares ----
// numpy pairwise_sum(n=2048): 16 leaves of 128 (8-accumulator unrolled loop,
// ((r0+r1)+(r2+r3))+((r4+r5)+(r6+r7))), balanced binary combine tree.
// Vector form: acc0[j] == rr[j], acc1[j] == rr[4+j] -- identical FP order.
__global__ __launch_bounds__(64)
void cvt_rows(const float* __restrict__ src, u16* __restrict__ dst,
              float* __restrict__ sq)
{
#pragma clang fp contract(off)
  const int row = blockIdx.x;
  const int l = threadIdx.x;
  const float* r = src + (size_t)row * 2048;
  const f32x4* r4 = (const f32x4*)r;
  ushort4* d4 = (ushort4*)(dst + (size_t)row * 2048);
#pragma unroll
  for (int i = 0; i < 8; i++){
    f32x4 v = r4[l + 64*i];
    ushort4 o;
    o.x = f2bf(v.x); o.y = f2bf(v.y); o.z = f2bf(v.z); o.w = f2bf(v.w);
    d4[l + 64*i] = o;
  }
  float leaf = 0.f;
  if (l < 16){
    const f32x4* p4 = (const f32x4*)(r + l*128);
    f32x4 a0 = {0.f,0.f,0.f,0.f}, a1 = {0.f,0.f,0.f,0.f};
#pragma unroll
    for (int i = 0; i < 32; i += 2){
      f32x4 v0 = p4[i], v1 = p4[i+1];
      a0 = a0 + v0*v0;
      a1 = a1 + v1*v1;
    }
    leaf = ((a0.x+a0.y)+(a0.z+a0.w))+((a1.x+a1.y)+(a1.z+a1.w));
  }
#pragma unroll
  for (int s = 1; s < 16; s <<= 1){
    float o = __shfl_down(leaf, s);
    if ((l & (2*s - 1)) == 0) leaf = leaf + o;
  }
  if (l == 0) sq[row] = leaf;
}

// ---- generic fp32 -> bf16 elementwise ----
__global__ __launch_bounds__(256)
void cvt_mat(const float* __restrict__ src, u16* __restrict__ dst, int n4)
{
  const f32x4* s4 = (const f32x4*)src;
  ushort4* d4 = (ushort4*)dst;
  for (int i = blockIdx.x*256 + threadIdx.x; i < n4; i += gridDim.x*256){
    f32x4 v = s4[i];
    ushort4 o;
    o.x = f2bf(v.x); o.y = f2bf(v.y); o.z = f2bf(v.z); o.w = f2bf(v.w);
    d4[i] = o;
  }
}

// ---- deep-pipelined bf16 GEMM  C = A[M,K] * B[N,K]^T ----
// BK=32, 4 LDS K-tile buffers, prefetch 3 tiles ahead, counted vmcnt(2*IF)
// (never 0 mid-loop), conflict-free XOR swizzle chunk' = chunk ^ ((row>>1)&3)
// [stage-source pre-swizzled so global_load_lds stays linear -- rule #21],
// setprio around MFMA, XCD-bijective block swizzle.
// Race-free: stage K(t+3) -> buf[(t+3)%4] = buf[(t-1)%4]; readers of that
// buffer completed their lgkmcnt waits (MFMA data dep) before arriving at the
// end-of-(t-1) barrier, which this wave crossed before issuing the stage.
// EPI 0: fp32 C.  EPI 1: relu(C+bias)->bf16.  EPI 2: C+bias fp32 packed
// ldc=ncols guard col<ncols.  EPI 3: plain bf16 C.
template<int BM, int BN, int WM, int WN, int EPI, int MINW>
__global__ __launch_bounds__(WM*WN*64, MINW)
void gemm_p(const u16* __restrict__ A, const u16* __restrict__ Bm,
            float* __restrict__ Cf, u16* __restrict__ Cb,
            const float* __restrict__ bias,
            int M, int N, int K, int ncols, int nbn)
{
  constexpr int T  = WM*WN*64;
  constexpr int FM = BM/(WM*16);
  constexpr int FN = BN/(WN*16);
  constexpr int ABYTES = BM*64;            // bytes per A K-tile (BK=32 bf16)
  constexpr int BUFB   = (BM+BN)*64;       // bytes per buffer (A then B)
  constexpr int RA = ABYTES/(T*16);        // stage rounds for A
  constexpr int RB = (BN*64)/(T*16);       // stage rounds for B
  constexpr int IF = RA + RB;              // loads per K-tile
  constexpr int NPH = (FM*FN >= 32) ? 2 : 1;
  extern __shared__ char lds[];

  const int t = threadIdx.x;
  const int nwg = gridDim.x;
  const int cpx = nwg >> 3;
  const int bid = blockIdx.x;
  const int wg  = (bid & 7)*cpx + (bid >> 3);   // XCD swizzle (nwg%8==0)
  const int bm = wg / nbn, bn = wg % nbn;
  const int brow = bm*BM, bcol = bn*BN;

  const int l = t & 63, w = t >> 6;
  const int wm = w / WN, wn = w % WN;
  const int wr = wm*(FM*16), wc = wn*(FN*16);
  const int fr = l & 15, fk = (l >> 4)*8;
  const int xk = fk ^ (((fr >> 1) & 3) << 3);   // conflict-free read col (u16)

  const int srow = t >> 2;                      // staging row within round
  const int scol = ((t & 3)*8) ^ (((t >> 3) & 3) << 3); // inverse-swz source

  const u16* agp[RA]; const u16* bgp[RB];
#pragma unroll
  for (int r = 0; r < RA; r++)
    agp[r] = A + (size_t)(brow + r*(T>>2) + srow)*K + scol;
#pragma unroll
  for (int r = 0; r < RB; r++)
    bgp[r] = Bm + (size_t)(bcol + r*(T>>2) + srow)*K + scol;

  f32x4 acc[FM][FN] = {};
  const int nt = K >> 5;

  auto stageA = [&](int kt, int buf){
    char* dst = lds + buf*BUFB + t*16;
#pragma unroll
    for (int r = 0; r < RA; r++)
      gload16(agp[r] + (kt << 5), (u16*)(dst + r*T*16));
  };
  auto stageB = [&](int kt, int buf){
    char* dst = lds + buf*BUFB + ABYTES + t*16;
#pragma unroll
    for (int r = 0; r < RB; r++)
      gload16(bgp[r] + (kt << 5), (u16*)(dst + r*T*16));
  };

  // prologue: K0,K1,K2 -> buf0,1,2; wait K0 (K1,K2 = 2*IF outstanding)
  stageA(0, 0); stageB(0, 0);
  stageA(1, 1); stageB(1, 1);
  stageA(2, 2); stageB(2, 2);
  waitcnt_vm<2*IF>();
  __builtin_amdgcn_s_barrier();

  for (int kt = 0; kt < nt; kt++){
    const int buf = kt & 3;
    const u16* As = (const u16*)(lds + buf*BUFB);
    const u16* Bs = (const u16*)(lds + buf*BUFB + ABYTES);
    const bool pre = (kt + 3 < nt);
    const int nbuf = (kt + 3) & 3;

    bf16x8 av[FM], bv[FN];
#pragma unroll
    for (int m = 0; m < FM; m++)
      av[m] = *(const bf16x8*)(As + (wr + m*16 + fr)*32 + xk);

    if (NPH == 1){
#pragma unroll
      for (int n = 0; n < FN; n++)
        bv[n] = *(const bf16x8*)(Bs + (wc + n*16 + fr)*32 + xk);
      if (pre){ stageA(kt + 3, nbuf); stageB(kt + 3, nbuf); }
      __builtin_amdgcn_s_barrier();
      __builtin_amdgcn_s_setprio(1);
#pragma unroll
      for (int m = 0; m < FM; m++)
#pragma unroll
        for (int n = 0; n < FN; n++)
          acc[m][n] = __builtin_amdgcn_mfma_f32_16x16x32_bf16(av[m], bv[n], acc[m][n], 0, 0, 0);
      __builtin_amdgcn_s_setprio(0);
    } else {
#pragma unroll
      for (int n = 0; n < FN/2; n++)
        bv[n] = *(const bf16x8*)(Bs + (wc + n*16 + fr)*32 + xk);
      if (pre) stageA(kt + 3, nbuf);
      __builtin_amdgcn_s_barrier();
      __builtin_amdgcn_s_setprio(1);
#pragma unroll
      for (int m = 0; m < FM; m++)
#pragma unroll
        for (int n = 0; n < FN/2; n++)
          acc[m][n] = __builtin_amdgcn_mfma_f32_16x16x32_bf16(av[m], bv[n], acc[m][n], 0, 0, 0);
      __builtin_amdgcn_s_setprio(0);

#pragma unroll
      for (int n = FN/2; n < FN; n++)
        bv[n] = *(const bf16x8*)(Bs + (wc + n*16 + fr)*32 + xk);
      if (pre) stageB(kt + 3, nbuf);
      __builtin_amdgcn_s_barrier();
      __builtin_amdgcn_s_setprio(1);
#pragma unroll
      for (int m = 0; m < FM; m++)
#pragma unroll
        for (int n = FN/2; n < FN; n++)
          acc[m][n] = __builtin_amdgcn_mfma_f32_16x16x32_bf16(av[m], bv[n], acc[m][n], 0, 0, 0);
      __builtin_amdgcn_s_setprio(0);
    }

    if (kt + 1 < nt){
      // keep tiles kt+2..kt+3 (that exist) in flight; wait kt+1 complete
      if (kt + 3 < nt)      waitcnt_vm<2*IF>();
      else if (kt + 2 < nt) waitcnt_vm<IF>();
      else                  waitcnt_vm<0>();
      __builtin_amdgcn_s_barrier();
    }
  }

#pragma unroll
  for (int n = 0; n < FN; n++){
    const int gcol = bcol + wc + n*16 + fr;
    float bvv = 0.f;
    if (EPI == 1) bvv = bias[gcol];
    if (EPI == 2 && gcol < ncols) bvv = bias[gcol];
#pragma unroll
    for (int m = 0; m < FM; m++){
      const int grow = brow + wr + m*16 + (l >> 4)*4;
#pragma unroll
      for (int r = 0; r < 4; r++){
        float v = acc[m][n][r];
        if (EPI == 0){
          Cf[(size_t)(grow + r)*N + gcol] = v;
        } else if (EPI == 1){
          Cb[(size_t)(grow + r)*N + gcol] = f2bf(fmaxf(v + bvv, 0.f));
        } else if (EPI == 2){
          if (gcol < ncols) Cf[(size_t)(grow + r)*ncols + gcol] = v + bvv;
        } else {
          Cb[(size_t)(grow + r)*N + gcol] = f2bf(v);
        }
      }
    }
  }
}

// ---- per-row: distances, argmin (exact fp64-refined candidates), softmax ----
__global__ __launch_bounds__(256)
void row_softmax(const u16* __restrict__ Sb, const float* __restrict__ x2,
                 const float* __restrict__ w2sq,
                 const float* __restrict__ x, const float* __restrict__ W,
                 u16* __restrict__ soft, float* __restrict__ winners)
{
  const int b = blockIdx.x, t = threadIdx.x;
  const float x2b = x2[b];
  const ushort4* S4 = (const ushort4*)(Sb + (size_t)b*4096);
  const f32x4* W24 = (const f32x4*)w2sq;
  float dv[16];
  float bd = 3.0e38f; int bc = 0;
#pragma unroll
  for (int i = 0; i < 4; i++){
    ushort4 s = S4[t + 256*i];
    f32x4 wv = W24[t + 256*i];
    float sf[4] = {bf2f(s.x), bf2f(s.y), bf2f(s.z), bf2f(s.w)};
#pragma unroll
    for (int j = 0; j < 4; j++){
      float u = x2b + wv[j];
      float d2 = u - 2.0f*sf[j];
      float d = __fsqrt_rn(fmaxf(d2, 1e-12f));
      dv[i*4 + j] = d;
      if (d < bd){ bd = d; bc = (t + 256*i)*4 + j; }
    }
  }
  u64 key = ((u64)__float_as_uint(bd) << 32) | (unsigned)bc;
#pragma unroll
  for (int s = 1; s < 64; s <<= 1){
    u64 o = __shfl_xor(key, s);
    if (o < key) key = o;
  }
  __shared__ u64 wk[4];
  __shared__ double csum[4];
  __shared__ float fred[4];
  __shared__ int ccnt;
  __shared__ int cand[32];
  if ((t & 63) == 0) wk[t >> 6] = key;
  if (t == 0) ccnt = 0;
  __syncthreads();
  u64 k0 = wk[0];
  if (wk[1] < k0) k0 = wk[1];
  if (wk[2] < k0) k0 = wk[2];
  if (wk[3] < k0) k0 = wk[3];
  const float dmin = __uint_as_float((unsigned)(k0 >> 32));

  const float thr = dmin + 0.01f;   // >>20 sigma of bf16 GEMM+storage noise
#pragma unroll
  for (int i = 0; i < 4; i++)
#pragma unroll
    for (int j = 0; j < 4; j++)
      if (dv[i*4 + j] <= thr){
        int p = atomicAdd(&ccnt, 1);
        if (p < 32) cand[p] = (t + 256*i)*4 + j;
      }
  __syncthreads();
  const int nc = min(ccnt, 32);

  float bestd = 3.0e38f; int besti = 0x7fffffff;
  const f32x4* xp = (const f32x4*)(x + (size_t)b*2048) + t*2;
  f32x4 xv0 = xp[0], xv1 = xp[1];
  for (int c = 0; c < nc; c++){
    const int h = cand[c];
    const f32x4* wp = (const f32x4*)(W + (size_t)h*2048) + t*2;
    f32x4 wv0 = wp[0], wv1 = wp[1];
    double a = 0.0;
#pragma unroll
    for (int j = 0; j < 4; j++) a += (double)xv0[j]*(double)wv0[j];
#pragma unroll
    for (int j = 0; j < 4; j++) a += (double)xv1[j]*(double)wv1[j];
#pragma unroll
    for (int s = 1; s < 64; s <<= 1) a += __shfl_xor(a, s);
    if ((t & 63) == 0) csum[t >> 6] = a;
    __syncthreads();
    if (t == 0){
      double tt = (csum[0] + csum[1]) + (csum[2] + csum[3]);
      float t32 = (float)tt;
      float u = x2b + w2sq[h];
      float d2 = u - 2.0f*t32;
      float d = __fsqrt_rn(fmaxf(d2, 1e-12f));
      if (d < bestd || (d == bestd && h < besti)){ bestd = d; besti = h; }
    }
    __syncthreads();
  }
  if (t == 0) winners[b] = (float)besti;

  float es = 0.f;
#pragma unroll
  for (int i = 0; i < 16; i++) es += __expf(-2.0f*(dv[i] - dmin));
#pragma unroll
  for (int s = 1; s < 64; s <<= 1) es += __shfl_xor(es, s);
  if ((t & 63) == 0) fred[t >> 6] = es;
  __syncthreads();
  const float tot = (fred[0] + fred[1]) + (fred[2] + fred[3]);
  const float inv = 1.0f / tot;
  ushort4* o4 = (ushort4*)(soft + (size_t)b*4096);
#pragma unroll
  for (int i = 0; i < 4; i++){
    ushort4 o;
    o.x = f2bf(__expf(-2.0f*(dv[i*4+0] - dmin))*inv);
    o.y = f2bf(__expf(-2.0f*(dv[i*4+1] - dmin))*inv);
    o.z = f2bf(__expf(-2.0f*(dv[i*4+2] - dmin))*inv);
    o.w = f2bf(__expf(-2.0f*(dv[i*4+3] - dmin))*inv);
    o4[t + 256*i] = o;
  }
}

extern "C" void kernel_launch(void* const* d_in, const int* in_sizes, int n_in,
                              void* d_out, int out_size, void* d_ws, size_t ws_size,
                              hipStream_t stream)
{
  const float* x  = (const float*)d_in[0];
  const float* Wk = (const float*)d_in[1];
  const float* w1 = (const float*)d_in[2];
  const float* b1 = (const float*)d_in[3];
  const float* w2 = (const float*)d_in[4];
  const float* b2 = (const float*)d_in[5];
  const float* w3 = (const float*)d_in[6];
  const float* b3 = (const float*)d_in[7];
  float* out = (float*)d_out;
  float* winners = out + (size_t)4096*1000;

  char* ws = (char*)d_ws;
  const size_t MB = 1u << 20;
  u16* Sb    = (u16*)(ws);                // 32MB bf16 S [dead after row_softmax]
  u16* xb    = (u16*)(ws + 32*MB);        // 16MB [dead after gemm1]
  u16* wb    = (u16*)(ws + 48*MB);        // 16MB [dead after gemm1]
  u16* soft  = (u16*)(ws + 32*MB);        // 32MB overlays xb/wb
  u16* w1b   = (u16*)(ws + 64*MB);        // 16MB
  u16* w2b   = (u16*)(ws + 80*MB);        // 4MB
  u16* w3b   = (u16*)(ws + 84*MB);        // 2MB (padded 1024x1024)
  float* x2  = (float*)(ws + 86*MB);      // 16KB
  float* w2s = x2 + 4096;                 // 16KB
  u16* h1    = (u16*)(ws);                // 16MB overlays Sb
  u16* h2    = (u16*)(ws + 16*MB);        // 8MB  overlays Sb

  cvt_rows<<<4096, 64, 0, stream>>>(x, xb, x2);
  cvt_rows<<<4096, 64, 0, stream>>>(Wk, wb, w2s);
  cvt_mat<<<2048, 256, 0, stream>>>(w1, w1b, 2048*4096/4);
  cvt_mat<<<1024, 256, 0, stream>>>(w2, w2b, 1024*2048/4);
  hipMemsetAsync(w3b, 0, (size_t)1024*1024*2, stream);
  cvt_mat<<<512, 256, 0, stream>>>(w3, w3b, 1000*1024/4);

  // S = x @ W^T  -> bf16 (256^2 tile, 8 waves, 128KB LDS, 4-deep pipe)
  hipFuncSetAttribute((const void*)gemm_p<256,256,2,4,3,2>,
                      hipFuncAttributeMaxDynamicSharedMemorySize, 4*512*64);
  gemm_p<256,256,2,4,3,2><<<256, 512, 4*512*64, stream>>>(
      xb, wb, nullptr, Sb, nullptr, 4096, 4096, 2048, 0, 16);

  // distances -> winners (exact refine) + soft (bf16)
  row_softmax<<<4096, 256, 0, stream>>>(Sb, x2, w2s, x, Wk, soft, winners);

  // h1 = relu(soft @ w1^T + b1)   (256x128 tile, 8 waves of 64x64, 96KB LDS)
  hipFuncSetAttribute((const void*)gemm_p<256,128,4,2,1,2>,
                      hipFuncAttributeMaxDynamicSharedMemorySize, 4*384*64);
  gemm_p<256,128,4,2,1,2><<<256, 512, 4*384*64, stream>>>(
      soft, w1b, nullptr, h1, b1, 4096, 2048, 4096, 0, 16);

  // h2 = relu(h1 @ w2^T + b2)   (128^2 tile, 4 waves of 64x64, 64KB LDS)
  hipFuncSetAttribute((const void*)gemm_p<128,128,2,2,1,3>,
                      hipFuncAttributeMaxDynamicSharedMemorySize, 4*256*64);
  gemm_p<128,128,2,2,1,3><<<256, 256, 4*256*64, stream>>>(
      h1, w2b, nullptr, h2, b2, 4096, 1024, 2048, 0, 8);

  // out = h2 @ w3^T + b3  (fp32, 1000 valid cols)
  hipFuncSetAttribute((const void*)gemm_p<128,128,2,2,2,3>,
                      hipFuncAttributeMaxDynamicSharedMemorySize, 4*256*64);
  gemm_p<128,128,2,2,2,3><<<256, 256, 4*256*64, stream>>>(
      h2, w3b, out, nullptr, b3, 4096, 1024, 1024, 1000, 8);
}